// Round 8
// baseline (188.675 us; speedup 1.0000x reference)
//
#include <hip/hip_runtime.h>

#define BC 4096      // rows of hidden_current
#define BP 8192      // rows of hidden_previous
#define D  768
#define KNB 5
#define TOPK 6
#define NT (BP / 128)   // 64 column tiles of the similarity matrix

typedef __bf16 bf16x8 __attribute__((ext_vector_type(8)));
typedef float  f32x4  __attribute__((ext_vector_type(4)));

__device__ __forceinline__ unsigned short f2bf(float f) {
    unsigned int u = __float_as_uint(f);
    u += 0x7fffu + ((u >> 16) & 1u);          // round-to-nearest-even
    return (unsigned short)(u >> 16);
}

__device__ __forceinline__ void gload16(const void* g, void* l) {
    __builtin_amdgcn_global_load_lds(
        (const __attribute__((address_space(1))) unsigned int*)g,
        (__attribute__((address_space(3))) unsigned int*)l, 16, 0, 0);
}

// Branchless insertion network, STATIC indices only (r6 lesson: runtime-indexed
// private arrays -> scratch). Strict >: ties keep the incumbent (earlier j),
// matching reference sequential j-ascending top_k.
__device__ __forceinline__ void topk_insert(float v, int j, float* bv, int* bj) {
    #pragma unroll
    for (int q = TOPK - 1; q >= 1; q--) {
        bool up   = v > bv[q - 1];
        bool here = (v > bv[q]) && !up;
        bv[q] = up ? bv[q - 1] : (here ? v : bv[q]);
        bj[q] = up ? bj[q - 1] : (here ? j : bj[q]);
    }
    if (v > bv[0]) { bv[0] = v; bj[0] = j; }
}

// ---------------- fused normalize: hp -> bf16 ranking copy, hc -> fp32 + sq ------
// Also zeroes out[0] (accumulated via atomics by k_mergeloss later in-stream).
__global__ __launch_bounds__(256) void k_norm(const float* __restrict__ hp,
                                              const float* __restrict__ hc,
                                              unsigned short* __restrict__ hpnb,
                                              float* __restrict__ hcn,
                                              float* __restrict__ sqout,
                                              float* __restrict__ out) {
    int b = blockIdx.x;
    int t = threadIdx.x;
    if (b == 0 && t == 0) out[0] = 0.0f;
    bool isP = (b < BP);
    int row = isP ? b : (b - BP);
    const float* xr = (isP ? hp : hc) + (size_t)row * D;
    float v0 = xr[t], v1 = xr[t + 256], v2 = xr[t + 512];
    float s = v0 * v0 + v1 * v1 + v2 * v2;
    #pragma unroll
    for (int off = 32; off; off >>= 1) s += __shfl_xor(s, off, 64);
    __shared__ float wsum[4];
    if ((t & 63) == 0) wsum[t >> 6] = s;
    __syncthreads();
    float tot = wsum[0] + wsum[1] + wsum[2] + wsum[3];
    float rinv = 1.0f / fmaxf(sqrtf(tot), 1e-12f);
    if (isP) {
        unsigned short* yr = hpnb + (size_t)row * D;
        yr[t] = f2bf(v0 * rinv); yr[t + 256] = f2bf(v1 * rinv); yr[t + 512] = f2bf(v2 * rinv);
    } else {
        float* yr = hcn + (size_t)row * D;
        yr[t] = v0 * rinv; yr[t + 256] = v1 * rinv; yr[t + 512] = v2 * rinv;
        if (t == 0) sqout[row] = tot * rinv * rinv;
    }
}

// ---------------- bf16 MFMA similarity tile + fused per-row top-6 ----------------
// grid (32, 64): 128x128 tile of S = hp_bf16[0:4096] . hp_bf16^T
// Staging: global_load_lds width=16, MONOTONE lane->address map (lane l -> row
// l>>3, chunk l&7; each 8-lane group = one 128-B line, in order). r2's 5x
// regression came from XOR-permuting the per-lane global addresses; r7's VGPR
// round-trip cost 50% VALUBusy. This is the m97 pattern (874 TF proven).
// LDS is unswizzled row-major [row][64k]; fragment ds_read_b128 takes 16-way
// bank conflicts, tolerated per m97/m98 (LDS pipe overlaps MFMA across waves).
__global__ __launch_bounds__(256, 3) void k_simtop(const unsigned short* __restrict__ hp,
                                                   float* __restrict__ candv,
                                                   int* __restrict__ candi) {
    __shared__ char smem[39424];
    unsigned short* sA = (unsigned short*)smem;          // [128 rows][64 k]
    unsigned short* sB = sA + 128 * 64;
    float* sS = (float*)smem;                            // [128][65] score buffer (alias)
    float* mv = (float*)(smem + 33280);                  // [128][6] partner top-6 vals
    int*   mj = (int*)(smem + 33280 + 3072);             // [128][6] partner top-6 idx

    const int t = threadIdx.x;
    const int l = t & 63;
    const int w = t >> 6;
    const int l15 = l & 15, quad = l >> 4;
    const int wr = w >> 1, wc = w & 1;
    const int ri = blockIdx.x, ci = blockIdx.y;

    // per-lane global source: row group w*32 + p*8 + (l>>3), chunk l&7 (monotone)
    const int srow = l >> 3, sch = l & 7;
    const unsigned short* Ag = hp + (size_t)(ri * 128 + w * 32 + srow) * D + sch * 8;
    const unsigned short* Bg = hp + (size_t)(ci * 128 + w * 32 + srow) * D + sch * 8;
    unsigned short* la = sA + (w * 32) * 64;             // wave-uniform LDS bases
    unsigned short* lb = sB + (w * 32) * 64;

    f32x4 acc[4][4];
    #pragma unroll
    for (int i = 0; i < 4; i++)
        #pragma unroll
        for (int j = 0; j < 4; j++) acc[i][j] = (f32x4){0.f, 0.f, 0.f, 0.f};

    // fragment LDS chunk offsets (bytes): slab 0 -> quad, slab 1 -> quad+4
    const int ch0 = quad * 16;
    const int ch1 = (quad + 4) * 16;

    for (int kk = 0; kk < D; kk += 64) {
        __syncthreads();                                 // prev iter's LDS reads done
        #pragma unroll
        for (int p = 0; p < 4; p++) {
            gload16(Ag + (size_t)(p * 8) * D + kk, la + (p * 8) * 64);
            gload16(Bg + (size_t)(p * 8) * D + kk, lb + (p * 8) * 64);
        }
        __syncthreads();                                 // vmcnt drain + tile ready
        #pragma unroll
        for (int ks = 0; ks < 2; ks++) {
            const int ch = ks ? ch1 : ch0;
            bf16x8 af[4], bfr[4];
            #pragma unroll
            for (int mi = 0; mi < 4; mi++)
                af[mi] = *(const bf16x8*)((const char*)sA + (wr * 64 + mi * 16 + l15) * 128 + ch);
            #pragma unroll
            for (int ni = 0; ni < 4; ni++)
                bfr[ni] = *(const bf16x8*)((const char*)sB + (wc * 64 + ni * 16 + l15) * 128 + ch);
            #pragma unroll
            for (int mi = 0; mi < 4; mi++)
                #pragma unroll
                for (int ni = 0; ni < 4; ni++)
                    acc[mi][ni] = __builtin_amdgcn_mfma_f32_16x16x32_bf16(af[mi], bfr[ni], acc[mi][ni], 0, 0, 0);
        }
    }

    // epilogue: 2 dump phases of 64 cols; 256 threads scan 2-per-row (32 cols each)
    float bv[TOPK]; int bj[TOPK];
    #pragma unroll
    for (int s = 0; s < TOPK; s++) { bv[s] = -1e30f; bj[s] = 0x7fffffff; }

    const int erow = t & 127, scb = (t >> 7) * 32;
    #pragma unroll
    for (int h = 0; h < 2; h++) {
        __syncthreads();
        if (wc == h) {
            #pragma unroll
            for (int mi = 0; mi < 4; mi++)
                #pragma unroll
                for (int ni = 0; ni < 4; ni++) {
                    int colb = ni * 16 + l15;
                    int rowb = wr * 64 + mi * 16 + quad * 4;
                    f32x4 v = acc[mi][ni];
                    #pragma unroll
                    for (int r = 0; r < 4; r++) sS[(rowb + r) * 65 + colb] = v[r];
                }
        }
        __syncthreads();
        int jbase = ci * 128 + h * 64 + scb;
        for (int c = 0; c < 32; c++) {
            float v = sS[erow * 65 + scb + c];
            if (v > bv[TOPK - 1]) topk_insert(v, jbase + c, bv, bj);
        }
    }

    // merge the two half-row scanners
    __syncthreads();
    if (t >= 128) {
        #pragma unroll
        for (int s = 0; s < TOPK; s++) { mv[(t - 128) * TOPK + s] = bv[s]; mj[(t - 128) * TOPK + s] = bj[s]; }
    }
    __syncthreads();
    if (t < 128) {
        #pragma unroll
        for (int s0 = 0; s0 < TOPK; s0++) {
            float v = mv[t * TOPK + s0];
            if (v > bv[TOPK - 1]) topk_insert(v, mj[t * TOPK + s0], bv, bj);
        }
        size_t o = ((size_t)(ri * 128 + t) * NT + ci) * TOPK;
        #pragma unroll
        for (int s = 0; s < TOPK; s++) { candv[o + s] = bv[s]; candi[o + s] = bj[s]; }
    }
}

// ------- fused merge (wave-parallel) + sparse loss + global atomic accumulate ----
// 256-thread blocks, 4 rows/block (wave per row). Per wave: 6-round xor merge of
// the 64 per-tile sorted top-6 lists (low-lane base preserves earlier-j ties),
// then deferred-reduction loss: per-lane dot partials across all 5 neighbors,
// ONE wave reduction at the end. Clamp dropped: d2 = sqi+sqj-2dot with
// dot <= ~0.25 for distinct normalized vectors, so max(.,0) is dead.
__global__ __launch_bounds__(256) void k_mergeloss(const float* __restrict__ candv,
                                                   const int* __restrict__ candi,
                                                   const float* __restrict__ hcn,
                                                   const float* __restrict__ sq,
                                                   const int* __restrict__ labp,
                                                   float* __restrict__ out) {
    __shared__ float bsum[4];
    const int w = threadIdx.x >> 6, lane = threadIdx.x & 63;
    const int i = blockIdx.x * 4 + w;

    const float* cv = candv + ((size_t)i * NT + lane) * TOPK;
    const int*   cj = candi + ((size_t)i * NT + lane) * TOPK;
    float bv[TOPK]; int bj[TOPK];
    #pragma unroll
    for (int s = 0; s < TOPK; s++) { bv[s] = cv[s]; bj[s] = cj[s]; }

    #pragma unroll
    for (int off = 1; off < 64; off <<= 1) {
        float pv[TOPK]; int pj[TOPK];
        #pragma unroll
        for (int s = 0; s < TOPK; s++) {
            pv[s] = __shfl_xor(bv[s], off, 64);
            pj[s] = __shfl_xor(bj[s], off, 64);
        }
        bool ilow = (lane & off) == 0;
        float av[TOPK], iv[TOPK]; int aj[TOPK], ij[TOPK];
        #pragma unroll
        for (int s = 0; s < TOPK; s++) {
            av[s] = ilow ? bv[s] : pv[s];  aj[s] = ilow ? bj[s] : pj[s];
            iv[s] = ilow ? pv[s] : bv[s];  ij[s] = ilow ? pj[s] : bj[s];
        }
        #pragma unroll
        for (int s = 0; s < TOPK; s++)
            if (iv[s] > av[TOPK - 1]) topk_insert(iv[s], ij[s], av, aj);
        #pragma unroll
        for (int s = 0; s < TOPK; s++) { bv[s] = av[s]; bj[s] = aj[s]; }
    }

    // loss: ranks 1..5 (rank 0 is self). Deferred reduction.
    const float* hi = hcn + (size_t)i * D;
    float4 h0 = *(const float4*)(hi + lane * 4);
    float4 h1 = *(const float4*)(hi + lane * 4 + 256);
    float4 h2 = *(const float4*)(hi + lane * 4 + 512);
    float sqi = sq[i];
    int li = labp[i];
    float part = 0.f;          // per-lane: sum_s e_s * (-2) * dot_partial
    float base = 0.f;          // lane-0 only: sum_s e_s * (sqi + sqj)
    #pragma unroll
    for (int s = 1; s <= KNB; s++) {
        int j = bj[s];
        if (j >= BC) continue;
        const float* hj = hcn + (size_t)j * D;
        float4 g0 = *(const float4*)(hj + lane * 4);
        float4 g1 = *(const float4*)(hj + lane * 4 + 256);
        float4 g2 = *(const float4*)(hj + lane * 4 + 512);
        float d = h0.x * g0.x + h0.y * g0.y + h0.z * g0.z + h0.w * g0.w
                + h1.x * g1.x + h1.y * g1.y + h1.z * g1.z + h1.w * g1.w
                + h2.x * g2.x + h2.y * g2.y + h2.z * g2.z + h2.w * g2.w;
        float e = (li == labp[j]) ? 1.0f : -1.0f;
        part += e * (-2.0f) * d;
        if (lane == 0) base += e * (sqi + sq[j]);
    }
    part += base;              // only lane 0 carries base
    #pragma unroll
    for (int off = 32; off; off >>= 1) part += __shfl_xor(part, off, 64);
    if (lane == 0) bsum[w] = part;
    __syncthreads();
    if (threadIdx.x == 0) {
        float s = bsum[0] + bsum[1] + bsum[2] + bsum[3];
        unsafeAtomicAdd(out, 0.5f * s / ((float)BC * (float)BC));
    }
}

extern "C" void kernel_launch(void* const* d_in, const int* in_sizes, int n_in,
                              void* d_out, int out_size, void* d_ws, size_t ws_size,
                              hipStream_t stream) {
    const float* hc   = (const float*)d_in[0];  // hidden_current  (4096,768)
    const float* hp   = (const float*)d_in[1];  // hidden_previous (8192,768)
    const int*   labp = (const int*)d_in[3];    // labels_previous (8192,)
    float* out = (float*)d_out;

    // workspace layout (~38 MB)
    unsigned short* hpnb = (unsigned short*)d_ws;          // BP*D bf16
    float* hcn  = (float*)(hpnb + (size_t)BP * D);         // BC*D f32
    float* sq   = hcn + (size_t)BC * D;                    // BC
    float* candv = sq + BC;                                // BC*NT*TOPK
    int*   candi = (int*)(candv + (size_t)BC * NT * TOPK); // BC*NT*TOPK

    k_norm<<<dim3(BP + BC), dim3(256), 0, stream>>>(hp, hc, hpnb, hcn, sq, out);
    k_simtop<<<dim3(BC / 128, NT), dim3(256), 0, stream>>>(hpnb, candv, candi);
    k_mergeloss<<<dim3(BC / 4), dim3(256), 0, stream>>>(candv, candi, hcn, sq, labp, out);
}

// Round 10
// 183.662 us; speedup vs baseline: 1.0273x; 1.0273x over previous
//
#include <hip/hip_runtime.h>

#define BC 4096      // rows of hidden_current
#define BP 8192      // rows of hidden_previous
#define D  768
#define KNB 5
#define TOPK 6
#define NT (BP / 128)   // 64 column tiles of the similarity matrix

typedef __bf16 bf16x8 __attribute__((ext_vector_type(8)));
typedef float  f32x4  __attribute__((ext_vector_type(4)));

__device__ __forceinline__ unsigned short f2bf(float f) {
    unsigned int u = __float_as_uint(f);
    u += 0x7fffu + ((u >> 16) & 1u);          // round-to-nearest-even
    return (unsigned short)(u >> 16);
}

__device__ __forceinline__ void gload16(const void* g, void* l) {
    __builtin_amdgcn_global_load_lds(
        (const __attribute__((address_space(1))) unsigned int*)g,
        (__attribute__((address_space(3))) unsigned int*)l, 16, 0, 0);
}

// Branchless insertion network, STATIC indices only (r6 lesson: runtime-indexed
// private arrays -> scratch). Strict >: ties keep the incumbent (earlier j),
// matching reference sequential j-ascending top_k.
__device__ __forceinline__ void topk_insert(float v, int j, float* bv, int* bj) {
    #pragma unroll
    for (int q = TOPK - 1; q >= 1; q--) {
        bool up   = v > bv[q - 1];
        bool here = (v > bv[q]) && !up;
        bv[q] = up ? bv[q - 1] : (here ? v : bv[q]);
        bj[q] = up ? bj[q - 1] : (here ? j : bj[q]);
    }
    if (v > bv[0]) { bv[0] = v; bj[0] = j; }
}

// ---------------- fused normalize: hp -> bf16 ranking copy, hc -> fp32 + sq ------
// hpnb is written PRE-SWIZZLED: element e of row r is stored at e ^ ((r&7)<<3)
// (16B chunks XOR-rotated within each 128B group). The monotone global_load_lds
// staging in k_simtop then lands the XOR-swizzled LDS layout for free, making
// fragment ds_read_b128 conflict-free (r8: unswizzled reads = 16 lanes/quad on
// one 4-bank window = 2e7 conflicts). Writes stay within the same 128B lines,
// so k_norm's coalescing is unchanged. Also zeroes out[0] for the atomics.
__global__ __launch_bounds__(256) void k_norm(const float* __restrict__ hp,
                                              const float* __restrict__ hc,
                                              unsigned short* __restrict__ hpnb,
                                              float* __restrict__ hcn,
                                              float* __restrict__ sqout,
                                              float* __restrict__ out) {
    int b = blockIdx.x;
    int t = threadIdx.x;
    if (b == 0 && t == 0) out[0] = 0.0f;
    bool isP = (b < BP);
    int row = isP ? b : (b - BP);
    const float* xr = (isP ? hp : hc) + (size_t)row * D;
    float v0 = xr[t], v1 = xr[t + 256], v2 = xr[t + 512];
    float s = v0 * v0 + v1 * v1 + v2 * v2;
    #pragma unroll
    for (int off = 32; off; off >>= 1) s += __shfl_xor(s, off, 64);
    __shared__ float wsum[4];
    if ((t & 63) == 0) wsum[t >> 6] = s;
    __syncthreads();
    float tot = wsum[0] + wsum[1] + wsum[2] + wsum[3];
    float rinv = 1.0f / fmaxf(sqrtf(tot), 1e-12f);
    if (isP) {
        unsigned short* yr = hpnb + (size_t)row * D;
        int rx = (row & 7) << 3;                       // chunk swizzle (bits 3..5)
        yr[t ^ rx]         = f2bf(v0 * rinv);
        yr[(t + 256) ^ rx] = f2bf(v1 * rinv);
        yr[(t + 512) ^ rx] = f2bf(v2 * rinv);
    } else {
        float* yr = hcn + (size_t)row * D;
        yr[t] = v0 * rinv; yr[t + 256] = v1 * rinv; yr[t + 512] = v2 * rinv;
        if (t == 0) sqout[row] = tot * rinv * rinv;
    }
}

// ---------------- bf16 MFMA similarity tile + fused per-row top-6 ----------------
// grid (32, 64): 128x128 tile of S = hp_bf16[0:4096] . hp_bf16^T
// Staging: global_load_lds width=16, MONOTONE lane->address map (m97 pattern,
// zero staging VALU). Source hpnb is pre-swizzled (see k_norm), so LDS holds
// the XOR layout: LDS pos p of row r = original k-chunk p^(r&7). Fragment
// reads at (quad^ (l15&7))*16 are conflict-free (r3-r6 formula, absmax-0
// proven). This combines r8's free staging with r6's free reads.
__global__ __launch_bounds__(256, 3) void k_simtop(const unsigned short* __restrict__ hp,
                                                   float* __restrict__ candv,
                                                   int* __restrict__ candi) {
    __shared__ char smem[39424];
    unsigned short* sA = (unsigned short*)smem;          // [128 rows][64 k] swizzled
    unsigned short* sB = sA + 128 * 64;
    float* sS = (float*)smem;                            // [128][65] score buffer (alias)
    float* mv = (float*)(smem + 33280);                  // [128][6] partner top-6 vals
    int*   mj = (int*)(smem + 33280 + 3072);             // [128][6] partner top-6 idx

    const int t = threadIdx.x;
    const int l = t & 63;
    const int w = t >> 6;
    const int l15 = l & 15, quad = l >> 4;
    const int wr = w >> 1, wc = w & 1;
    const int ri = blockIdx.x, ci = blockIdx.y;

    // per-lane global source: row group w*32 + p*8 + (l>>3), chunk l&7 (monotone)
    const int srow = l >> 3, sch = l & 7;
    const unsigned short* Ag = hp + (size_t)(ri * 128 + w * 32 + srow) * D + sch * 8;
    const unsigned short* Bg = hp + (size_t)(ci * 128 + w * 32 + srow) * D + sch * 8;
    unsigned short* la = sA + (w * 32) * 64;             // wave-uniform LDS bases
    unsigned short* lb = sB + (w * 32) * 64;

    f32x4 acc[4][4];
    #pragma unroll
    for (int i = 0; i < 4; i++)
        #pragma unroll
        for (int j = 0; j < 4; j++) acc[i][j] = (f32x4){0.f, 0.f, 0.f, 0.f};

    // fragment LDS chunk offsets (lane-constant, conflict-free): original
    // k-chunk q of row r sits at LDS pos q^(r&7); frag rows have r&7 == l15&7.
    const int x7  = l15 & 7;
    const int ch0 = (quad ^ x7) * 16;
    const int ch1 = ((quad + 4) ^ x7) * 16;

    for (int kk = 0; kk < D; kk += 64) {
        __syncthreads();                                 // prev iter's LDS reads done
        #pragma unroll
        for (int p = 0; p < 4; p++) {
            gload16(Ag + (size_t)(p * 8) * D + kk, la + (p * 8) * 64);
            gload16(Bg + (size_t)(p * 8) * D + kk, lb + (p * 8) * 64);
        }
        __syncthreads();                                 // vmcnt drain + tile ready
        #pragma unroll
        for (int ks = 0; ks < 2; ks++) {
            const int ch = ks ? ch1 : ch0;
            bf16x8 af[4], bfr[4];
            #pragma unroll
            for (int mi = 0; mi < 4; mi++)
                af[mi] = *(const bf16x8*)((const char*)sA + (wr * 64 + mi * 16 + l15) * 128 + ch);
            #pragma unroll
            for (int ni = 0; ni < 4; ni++)
                bfr[ni] = *(const bf16x8*)((const char*)sB + (wc * 64 + ni * 16 + l15) * 128 + ch);
            #pragma unroll
            for (int mi = 0; mi < 4; mi++)
                #pragma unroll
                for (int ni = 0; ni < 4; ni++)
                    acc[mi][ni] = __builtin_amdgcn_mfma_f32_16x16x32_bf16(af[mi], bfr[ni], acc[mi][ni], 0, 0, 0);
        }
    }

    // epilogue: 2 dump phases of 64 cols; 256 threads scan 2-per-row (32 cols each)
    float bv[TOPK]; int bj[TOPK];
    #pragma unroll
    for (int s = 0; s < TOPK; s++) { bv[s] = -1e30f; bj[s] = 0x7fffffff; }

    const int erow = t & 127, scb = (t >> 7) * 32;
    #pragma unroll
    for (int h = 0; h < 2; h++) {
        __syncthreads();
        if (wc == h) {
            #pragma unroll
            for (int mi = 0; mi < 4; mi++)
                #pragma unroll
                for (int ni = 0; ni < 4; ni++) {
                    int colb = ni * 16 + l15;
                    int rowb = wr * 64 + mi * 16 + quad * 4;
                    f32x4 v = acc[mi][ni];
                    #pragma unroll
                    for (int r = 0; r < 4; r++) sS[(rowb + r) * 65 + colb] = v[r];
                }
        }
        __syncthreads();
        int jbase = ci * 128 + h * 64 + scb;
        for (int c = 0; c < 32; c++) {
            float v = sS[erow * 65 + scb + c];
            if (v > bv[TOPK - 1]) topk_insert(v, jbase + c, bv, bj);
        }
    }

    // merge the two half-row scanners
    __syncthreads();
    if (t >= 128) {
        #pragma unroll
        for (int s = 0; s < TOPK; s++) { mv[(t - 128) * TOPK + s] = bv[s]; mj[(t - 128) * TOPK + s] = bj[s]; }
    }
    __syncthreads();
    if (t < 128) {
        #pragma unroll
        for (int s0 = 0; s0 < TOPK; s0++) {
            float v = mv[t * TOPK + s0];
            if (v > bv[TOPK - 1]) topk_insert(v, mj[t * TOPK + s0], bv, bj);
        }
        size_t o = ((size_t)(ri * 128 + t) * NT + ci) * TOPK;
        #pragma unroll
        for (int s = 0; s < TOPK; s++) { candv[o + s] = bv[s]; candi[o + s] = bj[s]; }
    }
}

// ------- fused merge (wave-parallel) + sparse loss + global atomic accumulate ----
// 256-thread blocks, 4 rows/block (wave per row). Per wave: 6-round xor merge of
// the 64 per-tile sorted top-6 lists (low-lane base preserves earlier-j ties),
// then deferred-reduction loss: per-lane dot partials across all 5 neighbors,
// ONE wave reduction at the end. Clamp dropped: d2 = sqi+sqj-2dot with
// dot <= ~0.25 for distinct normalized vectors, so max(.,0) is dead.
__global__ __launch_bounds__(256) void k_mergeloss(const float* __restrict__ candv,
                                                   const int* __restrict__ candi,
                                                   const float* __restrict__ hcn,
                                                   const float* __restrict__ sq,
                                                   const int* __restrict__ labp,
                                                   float* __restrict__ out) {
    __shared__ float bsum[4];
    const int w = threadIdx.x >> 6, lane = threadIdx.x & 63;
    const int i = blockIdx.x * 4 + w;

    const float* cv = candv + ((size_t)i * NT + lane) * TOPK;
    const int*   cj = candi + ((size_t)i * NT + lane) * TOPK;
    float bv[TOPK]; int bj[TOPK];
    #pragma unroll
    for (int s = 0; s < TOPK; s++) { bv[s] = cv[s]; bj[s] = cj[s]; }

    #pragma unroll
    for (int off = 1; off < 64; off <<= 1) {
        float pv[TOPK]; int pj[TOPK];
        #pragma unroll
        for (int s = 0; s < TOPK; s++) {
            pv[s] = __shfl_xor(bv[s], off, 64);
            pj[s] = __shfl_xor(bj[s], off, 64);
        }
        bool ilow = (lane & off) == 0;
        float av[TOPK], iv[TOPK]; int aj[TOPK], ij[TOPK];
        #pragma unroll
        for (int s = 0; s < TOPK; s++) {
            av[s] = ilow ? bv[s] : pv[s];  aj[s] = ilow ? bj[s] : pj[s];
            iv[s] = ilow ? pv[s] : bv[s];  ij[s] = ilow ? pj[s] : bj[s];
        }
        #pragma unroll
        for (int s = 0; s < TOPK; s++)
            if (iv[s] > av[TOPK - 1]) topk_insert(iv[s], ij[s], av, aj);
        #pragma unroll
        for (int s = 0; s < TOPK; s++) { bv[s] = av[s]; bj[s] = aj[s]; }
    }

    // loss: ranks 1..5 (rank 0 is self). Deferred reduction.
    const float* hi = hcn + (size_t)i * D;
    float4 h0 = *(const float4*)(hi + lane * 4);
    float4 h1 = *(const float4*)(hi + lane * 4 + 256);
    float4 h2 = *(const float4*)(hi + lane * 4 + 512);
    float sqi = sq[i];
    int li = labp[i];
    float part = 0.f;          // per-lane: sum_s e_s * (-2) * dot_partial
    float base = 0.f;          // lane-0 only: sum_s e_s * (sqi + sqj)
    #pragma unroll
    for (int s = 1; s <= KNB; s++) {
        int j = bj[s];
        if (j >= BC) continue;
        const float* hj = hcn + (size_t)j * D;
        float4 g0 = *(const float4*)(hj + lane * 4);
        float4 g1 = *(const float4*)(hj + lane * 4 + 256);
        float4 g2 = *(const float4*)(hj + lane * 4 + 512);
        float d = h0.x * g0.x + h0.y * g0.y + h0.z * g0.z + h0.w * g0.w
                + h1.x * g1.x + h1.y * g1.y + h1.z * g1.z + h1.w * g1.w
                + h2.x * g2.x + h2.y * g2.y + h2.z * g2.z + h2.w * g2.w;
        float e = (li == labp[j]) ? 1.0f : -1.0f;
        part += e * (-2.0f) * d;
        if (lane == 0) base += e * (sqi + sq[j]);
    }
    part += base;              // only lane 0 carries base
    #pragma unroll
    for (int off = 32; off; off >>= 1) part += __shfl_xor(part, off, 64);
    if (lane == 0) bsum[w] = part;
    __syncthreads();
    if (threadIdx.x == 0) {
        float s = bsum[0] + bsum[1] + bsum[2] + bsum[3];
        unsafeAtomicAdd(out, 0.5f * s / ((float)BC * (float)BC));
    }
}

extern "C" void kernel_launch(void* const* d_in, const int* in_sizes, int n_in,
                              void* d_out, int out_size, void* d_ws, size_t ws_size,
                              hipStream_t stream) {
    const float* hc   = (const float*)d_in[0];  // hidden_current  (4096,768)
    const float* hp   = (const float*)d_in[1];  // hidden_previous (8192,768)
    const int*   labp = (const int*)d_in[3];    // labels_previous (8192,)
    float* out = (float*)d_out;

    // workspace layout (~38 MB)
    unsigned short* hpnb = (unsigned short*)d_ws;          // BP*D bf16 (pre-swizzled)
    float* hcn  = (float*)(hpnb + (size_t)BP * D);         // BC*D f32
    float* sq   = hcn + (size_t)BC * D;                    // BC
    float* candv = sq + BC;                                // BC*NT*TOPK
    int*   candi = (int*)(candv + (size_t)BC * NT * TOPK); // BC*NT*TOPK

    k_norm<<<dim3(BP + BC), dim3(256), 0, stream>>>(hp, hc, hpnb, hcn, sq, out);
    k_simtop<<<dim3(BC / 128, NT), dim3(256), 0, stream>>>(hpnb, candv, candi);
    k_mergeloss<<<dim3(BC / 4), dim3(256), 0, stream>>>(candv, candi, hcn, sq, labp, out);
}